// Round 1
// 304.453 us; speedup vs baseline: 1.1684x; 1.1684x over previous
//
#include <hip/hip_runtime.h>

#define IMG 56
#define CH  128
#define S2  49
#define DSP 3
#define MTS 50

// ---- manual LDS layout (bytes), total 54016 (<= 54613 -> 3 blocks/CU) ----
// ldsA  [0, 12544):      49 x 128 shorts, XOR-8-block swizzled.
//                        x-window bf16 (phase1 A), attn-out bf16 (phase4 A).
//                        (A-frag reads touch rows 49..63 -> in-bounds garbage, masked.)
// ldsQK [12544, 37632):  49 x 256 shorts, XOR-8-block swizzled; Q = cols 0..127, K = 128..255.
//                        AFTER the QK^T barrier reused as 4 per-wave P buffers
//                        (wave w at byte offset w*6272; 49 rows x 64 shorts, XOR-swizzled).
// ldsVT [37632, 54016):  128 x 64 shorts (V transposed: [dim][key], keys 49..63 zeroed).
// bias+mask table now lives in GLOBAL memory (4 precomputed variants in d_ws).
#define LDA   128
#define LDQK  256
#define LDP   64
#define LDVT  64
#define OFF_QK 12544
#define OFF_VT 37632
#define SMEM_BYTES 54016

typedef __attribute__((ext_vector_type(8))) short bf16x8;
typedef __attribute__((ext_vector_type(4))) float f32x4;

__device__ __forceinline__ unsigned short f2bs(float f) {   // f32 -> bf16 bits, RNE
    unsigned u = __float_as_uint(f);
    return (unsigned short)((u + 0x7fffu + ((u >> 16) & 1u)) >> 16);
}

__device__ __forceinline__ int idxA(int row, int col) {     // XOR-swizzle, stride 128 shorts
    return row * LDA + ((((col >> 3) ^ row) & 7) << 3) + ((col >> 3) & ~7) * 8 + (col & 7);
}
// NOTE: cols for ldsA are 0..127 -> (col>>3) in 0..15; keep the high block bit:
__device__ __forceinline__ int idxA2(int row, int col) {
    int blk = (col >> 3) ^ (row & 7);        // XOR only low 3 bits; (col>>3) <= 15, row&7 <= 7
    return row * LDA + blk * 8 + (col & 7);
}
__device__ __forceinline__ int idxQK(int row, int col) {    // stride 256 shorts, cols 0..255
    int blk = (col >> 3) ^ (row & 7);        // stays inside Q half / K half (low-3-bit XOR)
    return row * LDQK + blk * 8 + (col & 7);
}

// ---- prep kernel: bf16 weights + 4 bias/mask table variants into workspace ----
__global__ __launch_bounds__(256)
void swin_prep(const float* __restrict__ w_qkv,
               const float* __restrict__ w_out,
               const float* __restrict__ pe,
               unsigned short* __restrict__ wqb,
               unsigned short* __restrict__ wob,
               float* __restrict__ mt4)
{
    const int tid = (int)(blockIdx.x * blockDim.x + threadIdx.x);
    const int np  = (int)(gridDim.x * blockDim.x);
    for (int i = tid; i < 384 * CH; i += np) wqb[i] = f2bs(w_qkv[i]);
    for (int i = tid; i < CH * CH;  i += np) wob[i] = f2bs(w_out[i]);
    for (int i = tid; i < 4 * S2 * S2; i += np) {
        const int v  = i / (S2 * S2), r = i - v * (S2 * S2);
        const int ii = r / S2, jj = r - ii * S2;
        const int iy = ii / 7, ix = ii - iy * 7;
        const int jy = jj / 7, jx = jj - jy * 7;
        float val = pe[(jy - iy + 6) * 13 + (jx - ix + 6)];
        if ((v & 2) && ((iy >= 4) != (jy >= 4))) val = -1e30f;
        if ((v & 1) && ((ix >= 4) != (jx >= 4))) val = -1e30f;
        mt4[v * (S2 * MTS) + ii * MTS + jj] = val;
    }
}

__global__ __launch_bounds__(256, 3)
void swin_fused(const float* __restrict__ x,
                const unsigned short* __restrict__ wqb,
                const float* __restrict__ mt4,
                const unsigned short* __restrict__ wob,
                const float* __restrict__ b_out,
                float* __restrict__ out)
{
    __shared__ __align__(16) char smem[SMEM_BYTES];
    unsigned short* const ldsA  = (unsigned short*)smem;
    unsigned short* const ldsQK = (unsigned short*)(smem + OFF_QK);
    unsigned short* const ldsVT = (unsigned short*)(smem + OFF_VT);

    const int tid  = (int)threadIdx.x;
    const int wave = tid >> 6, lane = tid & 63;
    const int lm   = lane & 15, lq = lane >> 4;
    const int b    = (int)blockIdx.y;
    const int wh   = (int)blockIdx.x >> 3, ww = (int)blockIdx.x & 7;
    const bool my  = (wh == 7), mx = (ww == 7);
    const float* const mtg = mt4 + (((my ? 2 : 0) + (mx ? 1 : 0)) * (S2 * MTS));

    // ---- phase 0: zero VT, stage rolled x-window as bf16 (swizzled) ----
    {
        unsigned long long* vz = (unsigned long long*)(smem + OFF_VT);
        for (int i = tid; i < 2048; i += 256) vz[i] = 0ull;     // 16384 B
    }
    for (int idx = tid; idx < S2 * 32; idx += 256) {
        const int s  = idx >> 5, c4 = (idx & 31) << 2;
        const int iy = s / 7, ix = s - iy * 7;
        int gy = wh * 7 + iy + DSP; if (gy >= IMG) gy -= IMG;
        int gx = ww * 7 + ix + DSP; if (gx >= IMG) gx -= IMG;
        const float4 v = *(const float4*)(x + (size_t)((b * IMG + gy) * IMG + gx) * CH + c4);
        uint2 p;
        p.x = (unsigned)f2bs(v.x) | ((unsigned)f2bs(v.y) << 16);
        p.y = (unsigned)f2bs(v.z) | ((unsigned)f2bs(v.w) << 16);
        *(uint2*)(ldsA + idxA2(s, c4)) = p;
    }
    __syncthreads();

    // ---- phase 1: qkv = A @ w_qkv^T (MFMA). Q,K into ldsQK; V transposed into VT ----
    {
        bf16x8 af[4][4];
        #pragma unroll
        for (int mt = 0; mt < 4; ++mt)
            #pragma unroll
            for (int kt = 0; kt < 4; ++kt)
                af[mt][kt] = *(const bf16x8*)(ldsA + idxA2(mt * 16 + lm, kt * 32 + lq * 8));

        #pragma unroll
        for (int nt = 0; nt < 6; ++nt) {
            const int n0 = (wave * 6 + nt) * 16;
            const unsigned short* wb = wqb + (size_t)(n0 + lm) * CH + lq * 8;
            bf16x8 bf[4];
            #pragma unroll
            for (int kt = 0; kt < 4; ++kt)
                bf[kt] = *(const bf16x8*)(wb + kt * 32);
            f32x4 c0 = {0.f,0.f,0.f,0.f}, c1 = {0.f,0.f,0.f,0.f};
            f32x4 c2 = {0.f,0.f,0.f,0.f}, c3 = {0.f,0.f,0.f,0.f};
            #pragma unroll
            for (int kt = 0; kt < 4; ++kt) {
                c0 = __builtin_amdgcn_mfma_f32_16x16x32_bf16(af[0][kt], bf[kt], c0, 0, 0, 0);
                c1 = __builtin_amdgcn_mfma_f32_16x16x32_bf16(af[1][kt], bf[kt], c1, 0, 0, 0);
                c2 = __builtin_amdgcn_mfma_f32_16x16x32_bf16(af[2][kt], bf[kt], c2, 0, 0, 0);
                c3 = __builtin_amdgcn_mfma_f32_16x16x32_bf16(af[3][kt], bf[kt], c3, 0, 0, 0);
            }
            const int col = n0 + lm;
            #pragma unroll
            for (int mt = 0; mt < 4; ++mt) {
                const f32x4 c = (mt == 0) ? c0 : (mt == 1) ? c1 : (mt == 2) ? c2 : c3;
                const int rb = mt * 16 + lq * 4;
                #pragma unroll
                for (int r = 0; r < 4; ++r) {
                    const int row = rb + r;
                    if (row < S2) {
                        const unsigned short hv = f2bs(c[r]);
                        if (col < 256) {
                            ldsQK[idxQK(row, col)] = hv;
                        } else {
                            const int d   = col - 256;                // V dim 0..127
                            const int blk = (row >> 3) ^ (d & 7);     // XOR-block swizzle on key idx
                            ldsVT[d * LDVT + blk * 8 + (row & 7)] = hv;
                        }
                    }
                }
            }
        }
    }
    __syncthreads();

    // ---- phases 2+3: attention, wave = head, all on MFMA ----
    {
        const int h = wave;
        unsigned short* const ldsP = (unsigned short*)(smem + OFF_QK + wave * 6272);

        bf16x8 qa[4], kb[4];
        #pragma unroll
        for (int mt = 0; mt < 4; ++mt)
            qa[mt] = *(const bf16x8*)(ldsQK + idxQK(mt * 16 + lm, h * 32 + lq * 8));
        #pragma unroll
        for (int nt = 0; nt < 4; ++nt)
            kb[nt] = *(const bf16x8*)(ldsQK + idxQK(nt * 16 + lm, CH + h * 32 + lq * 8));

        f32x4 c[4][4];
        #pragma unroll
        for (int mt = 0; mt < 4; ++mt)
            #pragma unroll
            for (int nt = 0; nt < 4; ++nt) {
                f32x4 z = {0.f, 0.f, 0.f, 0.f};
                c[mt][nt] = __builtin_amdgcn_mfma_f32_16x16x32_bf16(qa[mt], kb[nt], z, 0, 0, 0);
            }

        __syncthreads();   // Q/K dead in LDS -> region becomes the P buffers

        bool colok[4];
        #pragma unroll
        for (int nt = 0; nt < 4; ++nt) colok[nt] = (nt * 16 + lm) < S2;

        // scale + bias + mask (from global precomputed table) -> softmax
        #pragma unroll
        for (int mt = 0; mt < 4; ++mt) {
            #pragma unroll
            for (int r = 0; r < 4; ++r) {
                const int row  = mt * 16 + lq * 4 + r;
                const int rowc = row < S2 ? row : (S2 - 1);
                const float* mrow = mtg + rowc * MTS + lm;
                #pragma unroll
                for (int nt = 0; nt < 4; ++nt) {
                    const float v = c[mt][nt][r] * 0.5f + mrow[nt * 16];
                    c[mt][nt][r] = colok[nt] ? v : -1e30f;
                }
                float mm = fmaxf(fmaxf(c[mt][0][r], c[mt][1][r]), fmaxf(c[mt][2][r], c[mt][3][r]));
                mm = fmaxf(mm, __shfl_xor(mm, 1));
                mm = fmaxf(mm, __shfl_xor(mm, 2));
                mm = fmaxf(mm, __shfl_xor(mm, 4));
                mm = fmaxf(mm, __shfl_xor(mm, 8));
                const float p0 = __expf(c[mt][0][r] - mm);
                const float p1 = __expf(c[mt][1][r] - mm);
                const float p2 = __expf(c[mt][2][r] - mm);
                const float p3 = __expf(c[mt][3][r] - mm);
                float ll = (p0 + p1) + (p2 + p3);
                ll += __shfl_xor(ll, 1);
                ll += __shfl_xor(ll, 2);
                ll += __shfl_xor(ll, 4);
                ll += __shfl_xor(ll, 8);
                const float inv = 1.0f / ll;
                c[mt][0][r] = p0 * inv; c[mt][1][r] = p1 * inv;
                c[mt][2][r] = p2 * inv; c[mt][3][r] = p3 * inv;
            }
        }

        // write P (bf16, XOR-swizzled); cols 49..63 are exact 0 (mask -> exp underflow)
        #pragma unroll
        for (int mt = 0; mt < 4; ++mt)
            #pragma unroll
            for (int r = 0; r < 4; ++r) {
                const int row = mt * 16 + lq * 4 + r;
                if (row < S2) {
                    #pragma unroll
                    for (int nt = 0; nt < 4; ++nt) {
                        const int col = nt * 16 + lm;
                        const int blk = (col >> 3) ^ (row & 7);
                        ldsP[row * LDP + blk * 8 + (col & 7)] = f2bs(c[mt][nt][r]);
                    }
                }
            }

        // PV: O = P @ V. A=P (per-wave LDS round-trip), B=V from VT.
        bf16x8 pa[4][2], vb[2][2];
        #pragma unroll
        for (int mt = 0; mt < 4; ++mt) {
            const int row = mt * 16 + lm;
            #pragma unroll
            for (int kt = 0; kt < 2; ++kt) {
                const int blk = (kt * 4 + lq) ^ (row & 7);
                pa[mt][kt] = *(const bf16x8*)(ldsP + row * LDP + blk * 8);
            }
        }
        #pragma unroll
        for (int nt = 0; nt < 2; ++nt) {
            const int d = h * 32 + nt * 16 + lm;
            #pragma unroll
            for (int kt = 0; kt < 2; ++kt) {
                const int blk = (kt * 4 + lq) ^ (d & 7);
                vb[nt][kt] = *(const bf16x8*)(ldsVT + d * LDVT + blk * 8);
            }
        }
        f32x4 oc[4][2];
        #pragma unroll
        for (int mt = 0; mt < 4; ++mt)
            #pragma unroll
            for (int nt = 0; nt < 2; ++nt) {
                f32x4 z = {0.f, 0.f, 0.f, 0.f};
                z = __builtin_amdgcn_mfma_f32_16x16x32_bf16(pa[mt][0], vb[nt][0], z, 0, 0, 0);
                oc[mt][nt] = __builtin_amdgcn_mfma_f32_16x16x32_bf16(pa[mt][1], vb[nt][1], z, 0, 0, 0);
            }

        // attn-out -> ldsA (x-window dead; P lives in the QK region, no conflict)
        #pragma unroll
        for (int mt = 0; mt < 4; ++mt)
            #pragma unroll
            for (int r = 0; r < 4; ++r) {
                const int row = mt * 16 + lq * 4 + r;
                if (row < S2) {
                    #pragma unroll
                    for (int nt = 0; nt < 2; ++nt)
                        ldsA[idxA2(row, h * 32 + nt * 16 + lm)] = f2bs(oc[mt][nt][r]);
                }
            }
    }
    __syncthreads();

    // ---- phase 4: out = attn @ w_out^T + b_out, scattered to rolled coords ----
    {
        bf16x8 af[4][4];
        #pragma unroll
        for (int mt = 0; mt < 4; ++mt)
            #pragma unroll
            for (int kt = 0; kt < 4; ++kt)
                af[mt][kt] = *(const bf16x8*)(ldsA + idxA2(mt * 16 + lm, kt * 32 + lq * 8));

        #pragma unroll
        for (int nt = 0; nt < 2; ++nt) {
            const int n0 = (wave * 2 + nt) * 16;
            const unsigned short* wb = wob + (size_t)(n0 + lm) * CH + lq * 8;
            bf16x8 bf[4];
            #pragma unroll
            for (int kt = 0; kt < 4; ++kt)
                bf[kt] = *(const bf16x8*)(wb + kt * 32);
            f32x4 c0 = {0.f,0.f,0.f,0.f}, c1 = {0.f,0.f,0.f,0.f};
            f32x4 c2 = {0.f,0.f,0.f,0.f}, c3 = {0.f,0.f,0.f,0.f};
            #pragma unroll
            for (int kt = 0; kt < 4; ++kt) {
                c0 = __builtin_amdgcn_mfma_f32_16x16x32_bf16(af[0][kt], bf[kt], c0, 0, 0, 0);
                c1 = __builtin_amdgcn_mfma_f32_16x16x32_bf16(af[1][kt], bf[kt], c1, 0, 0, 0);
                c2 = __builtin_amdgcn_mfma_f32_16x16x32_bf16(af[2][kt], bf[kt], c2, 0, 0, 0);
                c3 = __builtin_amdgcn_mfma_f32_16x16x32_bf16(af[3][kt], bf[kt], c3, 0, 0, 0);
            }
            const int col = n0 + lm;
            const float bo = b_out[col];
            #pragma unroll
            for (int mt = 0; mt < 4; ++mt) {
                const f32x4 c = (mt == 0) ? c0 : (mt == 1) ? c1 : (mt == 2) ? c2 : c3;
                const int rb = mt * 16 + lq * 4;
                #pragma unroll
                for (int r = 0; r < 4; ++r) {
                    const int s = rb + r;
                    if (s < S2) {
                        const int sy = s / 7, sx = s - sy * 7;
                        int gy = wh * 7 + sy + DSP; if (gy >= IMG) gy -= IMG;
                        int gx = ww * 7 + sx + DSP; if (gx >= IMG) gx -= IMG;
                        out[(size_t)((b * IMG + gy) * IMG + gx) * CH + col] = c[r] + bo;
                    }
                }
            }
        }
    }
}

extern "C" void kernel_launch(void* const* d_in, const int* in_sizes, int n_in,
                              void* d_out, int out_size, void* d_ws, size_t ws_size,
                              hipStream_t stream) {
    const float* x      = (const float*)d_in[0];
    const float* w_qkv  = (const float*)d_in[1];
    const float* pe     = (const float*)d_in[2];
    const float* w_out  = (const float*)d_in[3];
    const float* b_out  = (const float*)d_in[4];
    float* out = (float*)d_out;

    // workspace: [0,98304) wqkv bf16; [98304,131072) wout bf16; [131072,170272) 4x mask tables f32
    unsigned short* wqb = (unsigned short*)d_ws;
    unsigned short* wob = (unsigned short*)((char*)d_ws + 98304);
    float*          mt4 = (float*)((char*)d_ws + 131072);

    swin_prep<<<dim3(128), 256, 0, stream>>>(w_qkv, w_out, pe, wqb, wob, mt4);

    dim3 grid(64, 64);   // (windows, batch)
    swin_fused<<<grid, 256, 0, stream>>>(x, wqb, mt4, wob, b_out, out);
}

// Round 3
// 298.560 us; speedup vs baseline: 1.1915x; 1.0197x over previous
//
#include <hip/hip_runtime.h>

#define IMG 56
#define CH  128
#define S2  49
#define DSP 3
#define MTS 50
#define MVS 2500   // per-variant stride in mask table (49 rows x 50 + pad row)

// ---- manual LDS layout (bytes), total 39440 (<= 40960 -> 4 blocks/CU) ----
// ldsQK [0, 25088):       49 x 256 shorts, XOR-8-block swizzled; Q = cols 0..127, K = 128..255.
//                         AFTER the QK^T barrier reused as 4 per-wave P buffers
//                         (wave w at byte offset w*6272; 49 rows x 64 shorts, XOR-swizzled).
//                         (qa/kb/pa frag over-reads of rows 49..63 land in-bounds garbage,
//                          masked downstream.)
// union [25088, 39440):   time-shared:
//    - phase 0-1a: x-window bf16, 49 x 128 shorts XOR-swizzled (12544 B; mt=3 frag row clamped to 48)
//    - phase 1b-3a: V^T bf16, 128 dims x 56 keys (stride 56 shorts = 14336 B + 16 B read-pad).
//                   keys 49..55 zero-filled inline; key reads 56..63 hit next row (finite * P==0)
//                   except d=127 which hits the tail pad -> pad is ZEROED in phase 0 (NaN fix).
//    - phase 3b-4: attn-out bf16, 49 x 128 shorts XOR-swizzled.
// bias+mask table lives in GLOBAL memory (4 precomputed variants, L1-resident).
#define LDA   128
#define LDQK  256
#define LDP   64
#define LDVT  56
#define OFF_U 25088
#define SMEM_BYTES 39440

typedef __attribute__((ext_vector_type(8))) short bf16x8;
typedef __attribute__((ext_vector_type(4))) float f32x4;

__device__ __forceinline__ unsigned short f2bs(float f) {   // f32 -> bf16 bits, RNE
    unsigned u = __float_as_uint(f);
    return (unsigned short)((u + 0x7fffu + ((u >> 16) & 1u)) >> 16);
}

__device__ __forceinline__ int idxA2(int row, int col) {    // XOR-swizzle, stride 128 shorts
    int blk = (col >> 3) ^ (row & 7);
    return row * LDA + blk * 8 + (col & 7);
}
__device__ __forceinline__ int idxQK(int row, int col) {    // stride 256 shorts, cols 0..255
    int blk = (col >> 3) ^ (row & 7);        // low-3-bit XOR stays inside Q half / K half
    return row * LDQK + blk * 8 + (col & 7);
}

// ---- prep kernel: bf16 weights + 4 bias/mask table variants into workspace ----
__global__ __launch_bounds__(256)
void swin_prep(const float* __restrict__ w_qkv,
               const float* __restrict__ w_out,
               const float* __restrict__ pe,
               unsigned short* __restrict__ wqb,
               unsigned short* __restrict__ wob,
               float* __restrict__ mt4)
{
    const int tid = (int)(blockIdx.x * blockDim.x + threadIdx.x);
    const int np  = (int)(gridDim.x * blockDim.x);
    for (int i = tid; i < 384 * CH; i += np) wqb[i] = f2bs(w_qkv[i]);
    for (int i = tid; i < CH * CH;  i += np) wob[i] = f2bs(w_out[i]);
    for (int i = tid; i < 4 * S2 * S2; i += np) {
        const int v  = i / (S2 * S2), r = i - v * (S2 * S2);
        const int ii = r / S2, jj = r - ii * S2;
        const int iy = ii / 7, ix = ii - iy * 7;
        const int jy = jj / 7, jx = jj - jy * 7;
        float val = pe[(jy - iy + 6) * 13 + (jx - ix + 6)];
        if ((v & 2) && ((iy >= 4) != (jy >= 4))) val = -1e30f;
        if ((v & 1) && ((ix >= 4) != (jx >= 4))) val = -1e30f;
        mt4[v * MVS + ii * MTS + jj] = val;
    }
}

__global__ __launch_bounds__(256, 4)
void swin_fused(const float* __restrict__ x,
                const unsigned short* __restrict__ wqb,
                const float* __restrict__ mt4,
                const unsigned short* __restrict__ wob,
                const float* __restrict__ b_out,
                float* __restrict__ out)
{
    __shared__ __align__(16) char smem[SMEM_BYTES];
    unsigned short* const ldsQK = (unsigned short*)smem;
    unsigned short* const ldsU  = (unsigned short*)(smem + OFF_U);   // x / V^T / attn-out

    const int tid  = (int)threadIdx.x;
    const int wave = tid >> 6, lane = tid & 63;
    const int lm   = lane & 15, lq = lane >> 4;
    const int b    = (int)blockIdx.y;
    const int wh   = (int)blockIdx.x >> 3, ww = (int)blockIdx.x & 7;
    const bool my  = (wh == 7), mx = (ww == 7);
    const float* const mtg = mt4 + (((my ? 2 : 0) + (mx ? 1 : 0)) * MVS);

    // ---- phase 0: zero V^T tail pad (NaN fix), stage rolled x-window as bf16 (swizzled) ----
    if (tid < 2) ((unsigned long long*)(smem + OFF_U + 2 * (size_t)CH * LDVT))[tid] = 0ull;
    for (int idx = tid; idx < S2 * 32; idx += 256) {
        const int s  = idx >> 5, c4 = (idx & 31) << 2;
        const int iy = s / 7, ix = s - iy * 7;
        int gy = wh * 7 + iy + DSP; if (gy >= IMG) gy -= IMG;
        int gx = ww * 7 + ix + DSP; if (gx >= IMG) gx -= IMG;
        const float4 v = *(const float4*)(x + (size_t)((b * IMG + gy) * IMG + gx) * CH + c4);
        uint2 p;
        p.x = (unsigned)f2bs(v.x) | ((unsigned)f2bs(v.y) << 16);
        p.y = (unsigned)f2bs(v.z) | ((unsigned)f2bs(v.w) << 16);
        *(uint2*)(ldsU + idxA2(s, c4)) = p;
    }
    __syncthreads();

    // ---- phase 1: qkv = A @ w_qkv^T (MFMA). Q,K into ldsQK; V^T (packed b64) into union ----
    {
        bf16x8 af[4][4];
        #pragma unroll
        for (int mt = 0; mt < 4; ++mt) {
            const int row = (mt < 3) ? (mt * 16 + lm) : 48;   // mt=3: clamp; rows 49..63 discarded
            #pragma unroll
            for (int kt = 0; kt < 4; ++kt)
                af[mt][kt] = *(const bf16x8*)(ldsU + idxA2(row, kt * 32 + lq * 8));
        }
        __syncthreads();   // x-window dead -> union region becomes V^T

        #pragma unroll
        for (int nt = 0; nt < 6; ++nt) {
            const int n0 = (wave * 6 + nt) * 16;
            const unsigned short* wb = wqb + (size_t)(n0 + lm) * CH + lq * 8;
            bf16x8 bf[4];
            #pragma unroll
            for (int kt = 0; kt < 4; ++kt)
                bf[kt] = *(const bf16x8*)(wb + kt * 32);
            f32x4 c0 = {0.f,0.f,0.f,0.f}, c1 = {0.f,0.f,0.f,0.f};
            f32x4 c2 = {0.f,0.f,0.f,0.f}, c3 = {0.f,0.f,0.f,0.f};
            #pragma unroll
            for (int kt = 0; kt < 4; ++kt) {
                c0 = __builtin_amdgcn_mfma_f32_16x16x32_bf16(af[0][kt], bf[kt], c0, 0, 0, 0);
                c1 = __builtin_amdgcn_mfma_f32_16x16x32_bf16(af[1][kt], bf[kt], c1, 0, 0, 0);
                c2 = __builtin_amdgcn_mfma_f32_16x16x32_bf16(af[2][kt], bf[kt], c2, 0, 0, 0);
                c3 = __builtin_amdgcn_mfma_f32_16x16x32_bf16(af[3][kt], bf[kt], c3, 0, 0, 0);
            }
            const int col = n0 + lm;
            if (n0 < 256) {
                // Q/K: u16 scatter into swizzled ldsQK
                #pragma unroll
                for (int mt = 0; mt < 4; ++mt) {
                    const f32x4 c = (mt == 0) ? c0 : (mt == 1) ? c1 : (mt == 2) ? c2 : c3;
                    const int rb = mt * 16 + lq * 4;
                    #pragma unroll
                    for (int r = 0; r < 4; ++r) {
                        const int row = rb + r;
                        if (row < S2) ldsQK[idxQK(row, col)] = f2bs(c[r]);
                    }
                }
            } else {
                // V^T: pack 4 consecutive keys into one b64 write; zero-fill keys >= 49
                const int d = col - 256;
                #pragma unroll
                for (int mt = 0; mt < 4; ++mt) {
                    const f32x4 c = (mt == 0) ? c0 : (mt == 1) ? c1 : (mt == 2) ? c2 : c3;
                    const int rb = mt * 16 + lq * 4;
                    if (rb < LDVT) {
                        unsigned long long pk = 0;
                        #pragma unroll
                        for (int r = 0; r < 4; ++r) {
                            const unsigned short us = (rb + r < S2) ? f2bs(c[r]) : (unsigned short)0;
                            pk |= (unsigned long long)us << (16 * r);
                        }
                        *(unsigned long long*)(ldsU + (size_t)d * LDVT + rb) = pk;
                    }
                }
            }
        }
    }
    __syncthreads();

    // ---- phases 2+3: attention, wave = head, all on MFMA ----
    {
        const int h = wave;
        unsigned short* const ldsP = (unsigned short*)(smem + wave * 6272);

        bf16x8 qa[4], kb[4];
        #pragma unroll
        for (int mt = 0; mt < 4; ++mt)
            qa[mt] = *(const bf16x8*)(ldsQK + idxQK(mt * 16 + lm, h * 32 + lq * 8));
        #pragma unroll
        for (int nt = 0; nt < 4; ++nt)
            kb[nt] = *(const bf16x8*)(ldsQK + idxQK(nt * 16 + lm, CH + h * 32 + lq * 8));

        f32x4 c[4][4];
        #pragma unroll
        for (int mt = 0; mt < 4; ++mt)
            #pragma unroll
            for (int nt = 0; nt < 4; ++nt) {
                f32x4 z = {0.f, 0.f, 0.f, 0.f};
                c[mt][nt] = __builtin_amdgcn_mfma_f32_16x16x32_bf16(qa[mt], kb[nt], z, 0, 0, 0);
            }

        __syncthreads();   // Q/K dead in LDS -> region becomes the P buffers

        bool colok[4];
        #pragma unroll
        for (int nt = 0; nt < 4; ++nt) colok[nt] = (nt * 16 + lm) < S2;

        // scale + bias + mask -> softmax WITHOUT max-subtraction (valid-row scores bounded;
        // masked entries: bias = -1e30 -> expf == 0 exactly; garbage rows >= 49 discarded)
        #pragma unroll
        for (int mt = 0; mt < 4; ++mt) {
            #pragma unroll
            for (int r = 0; r < 4; ++r) {
                const int row  = mt * 16 + lq * 4 + r;
                const int rowc = row < S2 ? row : (S2 - 1);
                const float* mrow = mtg + rowc * MTS + lm;
                const float p0 = colok[0] ? __expf(c[mt][0][r] * 0.5f + mrow[0])  : 0.f;
                const float p1 = colok[1] ? __expf(c[mt][1][r] * 0.5f + mrow[16]) : 0.f;
                const float p2 = colok[2] ? __expf(c[mt][2][r] * 0.5f + mrow[32]) : 0.f;
                const float p3 = colok[3] ? __expf(c[mt][3][r] * 0.5f + mrow[48]) : 0.f;
                float ll = (p0 + p1) + (p2 + p3);
                ll += __shfl_xor(ll, 1);
                ll += __shfl_xor(ll, 2);
                ll += __shfl_xor(ll, 4);
                ll += __shfl_xor(ll, 8);
                const float inv = 1.0f / ll;
                c[mt][0][r] = p0 * inv; c[mt][1][r] = p1 * inv;
                c[mt][2][r] = p2 * inv; c[mt][3][r] = p3 * inv;
            }
        }

        // write P (bf16, XOR-swizzled); cols 49..63 are exact 0
        #pragma unroll
        for (int mt = 0; mt < 4; ++mt)
            #pragma unroll
            for (int r = 0; r < 4; ++r) {
                const int row = mt * 16 + lq * 4 + r;
                if (row < S2) {
                    #pragma unroll
                    for (int nt = 0; nt < 4; ++nt) {
                        const int col = nt * 16 + lm;
                        const int blk = (col >> 3) ^ (row & 7);
                        ldsP[row * LDP + blk * 8 + (col & 7)] = f2bs(c[mt][nt][r]);
                    }
                }
            }

        // PV: O = P @ V. A=P (per-wave LDS round-trip), B=V from V^T (stride-56, natural layout).
        bf16x8 pa[4][2], vb[2][2];
        #pragma unroll
        for (int mt = 0; mt < 4; ++mt) {
            const int row = mt * 16 + lm;
            #pragma unroll
            for (int kt = 0; kt < 2; ++kt) {
                const int blk = (kt * 4 + lq) ^ (row & 7);
                pa[mt][kt] = *(const bf16x8*)(ldsP + row * LDP + blk * 8);
            }
        }
        #pragma unroll
        for (int nt = 0; nt < 2; ++nt) {
            const int d = h * 32 + nt * 16 + lm;
            #pragma unroll
            for (int kt = 0; kt < 2; ++kt)
                vb[nt][kt] = *(const bf16x8*)(ldsU + (size_t)d * LDVT + kt * 32 + lq * 8);
        }
        __syncthreads();   // V^T dead -> union region becomes attn-out

        f32x4 oc[4][2];
        #pragma unroll
        for (int mt = 0; mt < 4; ++mt)
            #pragma unroll
            for (int nt = 0; nt < 2; ++nt) {
                f32x4 z = {0.f, 0.f, 0.f, 0.f};
                z = __builtin_amdgcn_mfma_f32_16x16x32_bf16(pa[mt][0], vb[nt][0], z, 0, 0, 0);
                oc[mt][nt] = __builtin_amdgcn_mfma_f32_16x16x32_bf16(pa[mt][1], vb[nt][1], z, 0, 0, 0);
            }

        // attn-out -> union region (swizzled)
        #pragma unroll
        for (int mt = 0; mt < 4; ++mt)
            #pragma unroll
            for (int r = 0; r < 4; ++r) {
                const int row = mt * 16 + lq * 4 + r;
                if (row < S2) {
                    #pragma unroll
                    for (int nt = 0; nt < 2; ++nt)
                        ldsU[idxA2(row, h * 32 + nt * 16 + lm)] = f2bs(oc[mt][nt][r]);
                }
            }
    }
    __syncthreads();

    // ---- phase 4: out = attn @ w_out^T + b_out, scattered to rolled coords ----
    {
        bf16x8 af[4][4];
        #pragma unroll
        for (int mt = 0; mt < 4; ++mt) {
            const int row = (mt < 3) ? (mt * 16 + lm) : 48;   // mt=3: clamp; rows 49..63 discarded
            #pragma unroll
            for (int kt = 0; kt < 4; ++kt)
                af[mt][kt] = *(const bf16x8*)(ldsU + idxA2(row, kt * 32 + lq * 8));
        }

        #pragma unroll
        for (int nt = 0; nt < 2; ++nt) {
            const int n0 = (wave * 2 + nt) * 16;
            const unsigned short* wb = wob + (size_t)(n0 + lm) * CH + lq * 8;
            bf16x8 bf[4];
            #pragma unroll
            for (int kt = 0; kt < 4; ++kt)
                bf[kt] = *(const bf16x8*)(wb + kt * 32);
            f32x4 c0 = {0.f,0.f,0.f,0.f}, c1 = {0.f,0.f,0.f,0.f};
            f32x4 c2 = {0.f,0.f,0.f,0.f}, c3 = {0.f,0.f,0.f,0.f};
            #pragma unroll
            for (int kt = 0; kt < 4; ++kt) {
                c0 = __builtin_amdgcn_mfma_f32_16x16x32_bf16(af[0][kt], bf[kt], c0, 0, 0, 0);
                c1 = __builtin_amdgcn_mfma_f32_16x16x32_bf16(af[1][kt], bf[kt], c1, 0, 0, 0);
                c2 = __builtin_amdgcn_mfma_f32_16x16x32_bf16(af[2][kt], bf[kt], c2, 0, 0, 0);
                c3 = __builtin_amdgcn_mfma_f32_16x16x32_bf16(af[3][kt], bf[kt], c3, 0, 0, 0);
            }
            const int col = n0 + lm;
            const float bo = b_out[col];
            #pragma unroll
            for (int mt = 0; mt < 4; ++mt) {
                const f32x4 c = (mt == 0) ? c0 : (mt == 1) ? c1 : (mt == 2) ? c2 : c3;
                const int rb = mt * 16 + lq * 4;
                #pragma unroll
                for (int r = 0; r < 4; ++r) {
                    const int s = rb + r;
                    if (s < S2) {
                        const int sy = s / 7, sx = s - sy * 7;
                        int gy = wh * 7 + sy + DSP; if (gy >= IMG) gy -= IMG;
                        int gx = ww * 7 + sx + DSP; if (gx >= IMG) gx -= IMG;
                        out[(size_t)((b * IMG + gy) * IMG + gx) * CH + col] = c[r] + bo;
                    }
                }
            }
        }
    }
}

extern "C" void kernel_launch(void* const* d_in, const int* in_sizes, int n_in,
                              void* d_out, int out_size, void* d_ws, size_t ws_size,
                              hipStream_t stream) {
    const float* x      = (const float*)d_in[0];
    const float* w_qkv  = (const float*)d_in[1];
    const float* pe     = (const float*)d_in[2];
    const float* w_out  = (const float*)d_in[3];
    const float* b_out  = (const float*)d_in[4];
    float* out = (float*)d_out;

    // workspace: [0,98304) wqkv bf16; [98304,131072) wout bf16; [131072,171072) 4x mask tables f32
    unsigned short* wqb = (unsigned short*)d_ws;
    unsigned short* wob = (unsigned short*)((char*)d_ws + 98304);
    float*          mt4 = (float*)((char*)d_ws + 131072);

    swin_prep<<<dim3(128), 256, 0, stream>>>(w_qkv, w_out, pe, wqb, wob, mt4);

    dim3 grid(64, 64);   // (windows, batch)
    swin_fused<<<grid, 256, 0, stream>>>(x, wqb, mt4, wob, b_out, out);
}

// Round 4
// 283.649 us; speedup vs baseline: 1.2541x; 1.0526x over previous
//
#include <hip/hip_runtime.h>

#define IMG 56
#define CH  128
#define S2  49
#define DSP 3
#define MTS 50
#define MVS 2500   // per-variant stride in mask table (49 rows x 50 + pad row)

// ---- manual LDS layout (bytes), total 39440 (<= 40960 -> 4 blocks/CU) ----
// ldsQK [0, 25088):       49 x 256 shorts, XOR-8-block swizzled; Q = cols 0..127, K = 128..255.
//                         AFTER the QK^T barrier reused as 4 per-wave P buffers
//                         (wave w at byte offset w*6272; 49 rows x 64 shorts, XOR-swizzled).
//                         (qa/kb/pa frag over-reads of rows 49..63 land in-bounds garbage,
//                          masked downstream.)
// union [25088, 39440):   time-shared:
//    - phase 0-1a: x-window bf16, 49 x 128 shorts XOR-swizzled (12544 B; mt=3 frag row clamped to 48)
//    - phase 1b-3a: V^T bf16, 128 dims x 56 keys (stride 56 shorts = 14336 B + 16 B read-pad).
//                   keys 49..55 zero-filled inline; key reads 56..63 hit next row (finite * P==0)
//                   except d=127 which hits the tail pad -> pad ZEROED in phase 0.
//    - phase 3b-4: attn-out bf16, 49 x 128 shorts XOR-swizzled.
// bias+mask table lives in GLOBAL memory (4 precomputed variants, L1/L2-resident).
#define LDA   128
#define LDQK  256
#define LDP   64
#define LDVT  56
#define OFF_U 25088
#define SMEM_BYTES 39440

typedef __attribute__((ext_vector_type(8))) short bf16x8;
typedef __attribute__((ext_vector_type(4))) float f32x4;

__device__ __forceinline__ unsigned short f2bs(float f) {   // f32 -> bf16 bits, RNE (prep kernel)
    unsigned u = __float_as_uint(f);
    return (unsigned short)((u + 0x7fffu + ((u >> 16) & 1u)) >> 16);
}

__device__ __forceinline__ unsigned cvtpk(float lo, float hi) {  // 2x f32 -> packed bf16 (RNE), 1 VALU op
    unsigned r;
    asm("v_cvt_pk_bf16_f32 %0, %1, %2" : "=v"(r) : "v"(lo), "v"(hi));
    return r;
}

__device__ __forceinline__ int idxA2(int row, int col) {    // XOR-swizzle, stride 128 shorts
    int blk = (col >> 3) ^ (row & 7);
    return row * LDA + blk * 8 + (col & 7);
}
__device__ __forceinline__ int idxQK(int row, int col) {    // stride 256 shorts, cols 0..255
    int blk = (col >> 3) ^ (row & 7);        // low-3-bit XOR stays inside Q half / K half
    return row * LDQK + blk * 8 + (col & 7);
}

// ---- prep kernel: bf16 weights + 4 bias/mask table variants into workspace ----
__global__ __launch_bounds__(256)
void swin_prep(const float* __restrict__ w_qkv,
               const float* __restrict__ w_out,
               const float* __restrict__ pe,
               unsigned short* __restrict__ wqb,
               unsigned short* __restrict__ wob,
               float* __restrict__ mt4)
{
    const int tid = (int)(blockIdx.x * blockDim.x + threadIdx.x);
    const int np  = (int)(gridDim.x * blockDim.x);
    for (int i = tid; i < 384 * CH; i += np) wqb[i] = f2bs(w_qkv[i]);
    for (int i = tid; i < CH * CH;  i += np) wob[i] = f2bs(w_out[i]);
    for (int i = tid; i < 4 * S2 * S2; i += np) {
        const int v  = i / (S2 * S2), r = i - v * (S2 * S2);
        const int ii = r / S2, jj = r - ii * S2;
        const int iy = ii / 7, ix = ii - iy * 7;
        const int jy = jj / 7, jx = jj - jy * 7;
        float val = pe[(jy - iy + 6) * 13 + (jx - ix + 6)];
        if ((v & 2) && ((iy >= 4) != (jy >= 4))) val = -1e30f;
        if ((v & 1) && ((ix >= 4) != (jx >= 4))) val = -1e30f;
        mt4[v * MVS + ii * MTS + jj] = val;
    }
}

__global__ __launch_bounds__(256, 4)
void swin_fused(const float* __restrict__ x,
                const unsigned short* __restrict__ wqb,
                const float* __restrict__ mt4,
                const unsigned short* __restrict__ wob,
                const float* __restrict__ b_out,
                float* __restrict__ out)
{
    __shared__ __align__(16) char smem[SMEM_BYTES];
    unsigned short* const ldsQK = (unsigned short*)smem;
    unsigned short* const ldsU  = (unsigned short*)(smem + OFF_U);   // x / V^T / attn-out

    const int tid  = (int)threadIdx.x;
    const int wave = tid >> 6, lane = tid & 63;
    const int lm   = lane & 15, lq = lane >> 4;
    const int b    = (int)blockIdx.y;
    const int wh   = (int)blockIdx.x >> 3, ww = (int)blockIdx.x & 7;
    const bool my  = (wh == 7), mx = (ww == 7);
    const float* const mtg = mt4 + (((my ? 2 : 0) + (mx ? 1 : 0)) * MVS);

    // ---- phase 0: load-burst x-window (7 x float4 in flight) + early weight prefetch ----
    float4 xv[7];
    #pragma unroll
    for (int p = 0; p < 7; ++p) {
        if (p < 6 || tid < 32) {
            const int idx = tid + p * 256;
            const int s  = idx >> 5, c4 = (idx & 31) << 2;
            const int iy = s / 7, ix = s - iy * 7;
            int gy = wh * 7 + iy + DSP; if (gy >= IMG) gy -= IMG;
            int gx = ww * 7 + ix + DSP; if (gx >= IMG) gx -= IMG;
            xv[p] = *(const float4*)(x + (size_t)((b * IMG + gy) * IMG + gx) * CH + c4);
        }
    }
    // rolling weight prefetch: wr[0..1] issued here, fly during phase 0
    bf16x8 wr[6][4];
    #pragma unroll
    for (int nt = 0; nt < 2; ++nt) {
        const unsigned short* wb = wqb + (size_t)((wave * 6 + nt) * 16 + lm) * CH + lq * 8;
        #pragma unroll
        for (int kt = 0; kt < 4; ++kt) wr[nt][kt] = *(const bf16x8*)(wb + kt * 32);
    }
    // zero V^T tail pad (survives: x-window ends at 12544 B, V^T writes stop at 14336 B)
    if (tid < 2) ((unsigned long long*)(smem + OFF_U + 2 * (size_t)CH * LDVT))[tid] = 0ull;
    // convert + store staged x
    #pragma unroll
    for (int p = 0; p < 7; ++p) {
        if (p < 6 || tid < 32) {
            const int idx = tid + p * 256;
            const int s  = idx >> 5, c4 = (idx & 31) << 2;
            uint2 pk;
            pk.x = cvtpk(xv[p].x, xv[p].y);
            pk.y = cvtpk(xv[p].z, xv[p].w);
            *(uint2*)(ldsU + idxA2(s, c4)) = pk;
        }
    }
    __syncthreads();

    // ---- phase 1: qkv = A @ w_qkv^T (MFMA). Q,K into ldsQK; V^T (packed b64) into union ----
    {
        bf16x8 af[4][4];
        #pragma unroll
        for (int mt = 0; mt < 4; ++mt) {
            const int row = (mt < 3) ? (mt * 16 + lm) : 48;   // mt=3: clamp; rows 49..63 discarded
            #pragma unroll
            for (int kt = 0; kt < 4; ++kt)
                af[mt][kt] = *(const bf16x8*)(ldsU + idxA2(row, kt * 32 + lq * 8));
        }
        __syncthreads();   // x-window dead -> union region becomes V^T

        #pragma unroll
        for (int nt = 0; nt < 6; ++nt) {
            if (nt < 4) {  // prefetch 2 ahead
                const unsigned short* wb = wqb + (size_t)((wave * 6 + nt + 2) * 16 + lm) * CH + lq * 8;
                #pragma unroll
                for (int kt = 0; kt < 4; ++kt) wr[nt + 2][kt] = *(const bf16x8*)(wb + kt * 32);
            }
            f32x4 c0 = {0.f,0.f,0.f,0.f}, c1 = {0.f,0.f,0.f,0.f};
            f32x4 c2 = {0.f,0.f,0.f,0.f}, c3 = {0.f,0.f,0.f,0.f};
            #pragma unroll
            for (int kt = 0; kt < 4; ++kt) {
                c0 = __builtin_amdgcn_mfma_f32_16x16x32_bf16(af[0][kt], wr[nt][kt], c0, 0, 0, 0);
                c1 = __builtin_amdgcn_mfma_f32_16x16x32_bf16(af[1][kt], wr[nt][kt], c1, 0, 0, 0);
                c2 = __builtin_amdgcn_mfma_f32_16x16x32_bf16(af[2][kt], wr[nt][kt], c2, 0, 0, 0);
                c3 = __builtin_amdgcn_mfma_f32_16x16x32_bf16(af[3][kt], wr[nt][kt], c3, 0, 0, 0);
            }
            const int n0  = (wave * 6 + nt) * 16;
            const int col = n0 + lm;
            if (n0 < 256) {
                // Q/K: u16 scatter (cvt_pk pairs along r)
                #pragma unroll
                for (int mt = 0; mt < 4; ++mt) {
                    const f32x4 c = (mt == 0) ? c0 : (mt == 1) ? c1 : (mt == 2) ? c2 : c3;
                    const int rb = mt * 16 + lq * 4;
                    #pragma unroll
                    for (int rp = 0; rp < 2; ++rp) {
                        const unsigned pk = cvtpk(c[2 * rp], c[2 * rp + 1]);
                        const int row0 = rb + 2 * rp;
                        if (row0 < S2)     ldsQK[idxQK(row0, col)]     = (unsigned short)pk;
                        if (row0 + 1 < S2) ldsQK[idxQK(row0 + 1, col)] = (unsigned short)(pk >> 16);
                    }
                }
            } else {
                // V^T: pack 4 consecutive keys into one b64 write; zero-fill keys >= 49
                const int d = col - 256;
                #pragma unroll
                for (int mt = 0; mt < 4; ++mt) {
                    const f32x4 c = (mt == 0) ? c0 : (mt == 1) ? c1 : (mt == 2) ? c2 : c3;
                    const int rb = mt * 16 + lq * 4;
                    if (rb < LDVT) {
                        const float e0 = (rb + 0 < S2) ? c[0] : 0.f;
                        const float e1 = (rb + 1 < S2) ? c[1] : 0.f;
                        const float e2 = (rb + 2 < S2) ? c[2] : 0.f;
                        const float e3 = (rb + 3 < S2) ? c[3] : 0.f;
                        const unsigned lo = cvtpk(e0, e1), hi = cvtpk(e2, e3);
                        *(unsigned long long*)(ldsU + (size_t)d * LDVT + rb) =
                            (unsigned long long)lo | ((unsigned long long)hi << 32);
                    }
                }
            }
        }
    }
    __syncthreads();

    // ---- phases 2+3: attention, wave = head, all on MFMA ----
    {
        const int h = wave;
        unsigned short* const ldsP = (unsigned short*)(smem + wave * 6272);

        bf16x8 qa[4], kb[4];
        #pragma unroll
        for (int mt = 0; mt < 4; ++mt)
            qa[mt] = *(const bf16x8*)(ldsQK + idxQK(mt * 16 + lm, h * 32 + lq * 8));
        #pragma unroll
        for (int nt = 0; nt < 4; ++nt)
            kb[nt] = *(const bf16x8*)(ldsQK + idxQK(nt * 16 + lm, CH + h * 32 + lq * 8));

        // mask/bias prefetch: [mt][r][nt]; group 0 issued before MFMA burst
        float mk[4][4][4];
        auto loadmk = [&](float (&dst)[4][4], int mtv) {
            #pragma unroll
            for (int r = 0; r < 4; ++r) {
                const int row  = mtv * 16 + lq * 4 + r;
                const int rowc = row < S2 ? row : (S2 - 1);
                const float* mrow = mtg + rowc * MTS + lm;
                #pragma unroll
                for (int nt = 0; nt < 4; ++nt) dst[r][nt] = mrow[nt * 16];
            }
        };
        loadmk(mk[0], 0);

        f32x4 c[4][4];
        __builtin_amdgcn_s_setprio(1);
        #pragma unroll
        for (int mt = 0; mt < 4; ++mt)
            #pragma unroll
            for (int nt = 0; nt < 4; ++nt) {
                f32x4 z = {0.f, 0.f, 0.f, 0.f};
                c[mt][nt] = __builtin_amdgcn_mfma_f32_16x16x32_bf16(qa[mt], kb[nt], z, 0, 0, 0);
            }
        __builtin_amdgcn_s_setprio(0);

        __syncthreads();   // Q/K dead in LDS -> region becomes the P buffers

        bool colok[4];
        #pragma unroll
        for (int nt = 0; nt < 4; ++nt) colok[nt] = (nt * 16 + lm) < S2;

        // scale + bias + mask -> softmax WITHOUT max-subtraction (valid-row scores bounded;
        // masked entries: bias = -1e30 -> expf == 0 exactly; garbage rows >= 49 discarded)
        #pragma unroll
        for (int mt = 0; mt < 4; ++mt) {
            if (mt < 3) loadmk(mk[mt + 1], mt + 1);   // prefetch next group
            #pragma unroll
            for (int r = 0; r < 4; ++r) {
                const float p0 = colok[0] ? __expf(c[mt][0][r] * 0.5f + mk[mt][r][0]) : 0.f;
                const float p1 = colok[1] ? __expf(c[mt][1][r] * 0.5f + mk[mt][r][1]) : 0.f;
                const float p2 = colok[2] ? __expf(c[mt][2][r] * 0.5f + mk[mt][r][2]) : 0.f;
                const float p3 = colok[3] ? __expf(c[mt][3][r] * 0.5f + mk[mt][r][3]) : 0.f;
                float ll = (p0 + p1) + (p2 + p3);
                ll += __shfl_xor(ll, 1);
                ll += __shfl_xor(ll, 2);
                ll += __shfl_xor(ll, 4);
                ll += __shfl_xor(ll, 8);
                const float inv = 1.0f / ll;
                c[mt][0][r] = p0 * inv; c[mt][1][r] = p1 * inv;
                c[mt][2][r] = p2 * inv; c[mt][3][r] = p3 * inv;
            }
        }

        // write P (bf16, XOR-swizzled, cvt_pk pairs); cols 49..63 are exact 0
        #pragma unroll
        for (int mt = 0; mt < 4; ++mt)
            #pragma unroll
            for (int nt = 0; nt < 4; ++nt) {
                const int col = nt * 16 + lm;
                #pragma unroll
                for (int rp = 0; rp < 2; ++rp) {
                    const unsigned pk = cvtpk(c[mt][nt][2 * rp], c[mt][nt][2 * rp + 1]);
                    const int row0 = mt * 16 + lq * 4 + 2 * rp;
                    if (row0 < S2) {
                        const int blk = (col >> 3) ^ (row0 & 7);
                        ldsP[row0 * LDP + blk * 8 + (col & 7)] = (unsigned short)pk;
                    }
                    if (row0 + 1 < S2) {
                        const int blk = (col >> 3) ^ ((row0 + 1) & 7);
                        ldsP[(row0 + 1) * LDP + blk * 8 + (col & 7)] = (unsigned short)(pk >> 16);
                    }
                }
            }

        // PV: O = P @ V. A=P (per-wave LDS round-trip), B=V from V^T (stride-56).
        bf16x8 pa[4][2], vb[2][2];
        #pragma unroll
        for (int mt = 0; mt < 4; ++mt) {
            const int row = mt * 16 + lm;
            #pragma unroll
            for (int kt = 0; kt < 2; ++kt) {
                const int blk = (kt * 4 + lq) ^ (row & 7);
                pa[mt][kt] = *(const bf16x8*)(ldsP + row * LDP + blk * 8);
            }
        }
        #pragma unroll
        for (int nt = 0; nt < 2; ++nt) {
            const int d = h * 32 + nt * 16 + lm;
            #pragma unroll
            for (int kt = 0; kt < 2; ++kt)
                vb[nt][kt] = *(const bf16x8*)(ldsU + (size_t)d * LDVT + kt * 32 + lq * 8);
        }
        // prefetch phase-4 weights + bias: in flight across barrier + PV + attn-out writes
        bf16x8 wo[2][4];
        #pragma unroll
        for (int nt = 0; nt < 2; ++nt) {
            const unsigned short* wb = wob + (size_t)((wave * 2 + nt) * 16 + lm) * CH + lq * 8;
            #pragma unroll
            for (int kt = 0; kt < 4; ++kt) wo[nt][kt] = *(const bf16x8*)(wb + kt * 32);
        }
        const float bo0 = b_out[wave * 32 + lm];
        const float bo1 = b_out[wave * 32 + 16 + lm];
        __syncthreads();   // V^T dead -> union region becomes attn-out

        f32x4 oc[4][2];
        __builtin_amdgcn_s_setprio(1);
        #pragma unroll
        for (int mt = 0; mt < 4; ++mt)
            #pragma unroll
            for (int nt = 0; nt < 2; ++nt) {
                f32x4 z = {0.f, 0.f, 0.f, 0.f};
                z = __builtin_amdgcn_mfma_f32_16x16x32_bf16(pa[mt][0], vb[nt][0], z, 0, 0, 0);
                oc[mt][nt] = __builtin_amdgcn_mfma_f32_16x16x32_bf16(pa[mt][1], vb[nt][1], z, 0, 0, 0);
            }
        __builtin_amdgcn_s_setprio(0);

        // attn-out -> union region (swizzled, cvt_pk pairs)
        #pragma unroll
        for (int mt = 0; mt < 4; ++mt)
            #pragma unroll
            for (int nt = 0; nt < 2; ++nt) {
                const int col = h * 32 + nt * 16 + lm;
                #pragma unroll
                for (int rp = 0; rp < 2; ++rp) {
                    const unsigned pk = cvtpk(oc[mt][nt][2 * rp], oc[mt][nt][2 * rp + 1]);
                    const int row0 = mt * 16 + lq * 4 + 2 * rp;
                    if (row0 < S2)     ldsU[idxA2(row0, col)]     = (unsigned short)pk;
                    if (row0 + 1 < S2) ldsU[idxA2(row0 + 1, col)] = (unsigned short)(pk >> 16);
                }
            }
        __syncthreads();

        // ---- phase 4: out = attn @ w_out^T + b_out; both nt tiles, then adjacent stores ----
        bf16x8 af[4][4];
        #pragma unroll
        for (int mt = 0; mt < 4; ++mt) {
            const int row = (mt < 3) ? (mt * 16 + lm) : 48;   // mt=3: clamp; rows 49..63 discarded
            #pragma unroll
            for (int kt = 0; kt < 4; ++kt)
                af[mt][kt] = *(const bf16x8*)(ldsU + idxA2(row, kt * 32 + lq * 8));
        }

        f32x4 d[2][4];
        #pragma unroll
        for (int nt = 0; nt < 2; ++nt)
            #pragma unroll
            for (int mt = 0; mt < 4; ++mt) {
                f32x4 acc = {0.f,0.f,0.f,0.f};
                #pragma unroll
                for (int kt = 0; kt < 4; ++kt)
                    acc = __builtin_amdgcn_mfma_f32_16x16x32_bf16(af[mt][kt], wo[nt][kt], acc, 0, 0, 0);
                d[nt][mt] = acc;
            }

        const int colb = wave * 32 + lm;
        #pragma unroll
        for (int mt = 0; mt < 4; ++mt)
            #pragma unroll
            for (int r = 0; r < 4; ++r) {
                const int s = mt * 16 + lq * 4 + r;
                if (s < S2) {
                    const int sy = s / 7, sx = s - sy * 7;
                    int gy = wh * 7 + sy + DSP; if (gy >= IMG) gy -= IMG;
                    int gx = ww * 7 + sx + DSP; if (gx >= IMG) gx -= IMG;
                    float* op = out + (size_t)((b * IMG + gy) * IMG + gx) * CH;
                    op[colb]      = d[0][mt][r] + bo0;   // adjacent 64 B halves ->
                    op[colb + 16] = d[1][mt][r] + bo1;   // one full 128 B line together
                }
            }
    }
}

extern "C" void kernel_launch(void* const* d_in, const int* in_sizes, int n_in,
                              void* d_out, int out_size, void* d_ws, size_t ws_size,
                              hipStream_t stream) {
    const float* x      = (const float*)d_in[0];
    const float* w_qkv  = (const float*)d_in[1];
    const float* pe     = (const float*)d_in[2];
    const float* w_out  = (const float*)d_in[3];
    const float* b_out  = (const float*)d_in[4];
    float* out = (float*)d_out;

    // workspace: [0,98304) wqkv bf16; [98304,131072) wout bf16; [131072,171072) 4x mask tables f32
    unsigned short* wqb = (unsigned short*)d_ws;
    unsigned short* wob = (unsigned short*)((char*)d_ws + 98304);
    float*          mt4 = (float*)((char*)d_ws + 131072);

    swin_prep<<<dim3(128), 256, 0, stream>>>(w_qkv, w_out, pe, wqb, wob, mt4);

    dim3 grid(64, 64);   // (windows, batch)
    swin_fused<<<grid, 256, 0, stream>>>(x, wqb, mt4, wob, b_out, out);
}